// Round 1
// baseline (217.136 us; speedup 1.0000x reference)
//
#include <hip/hip_runtime.h>
#include <math.h>

// FIRE bias: out[h,i,j] = MLP(nd(i,j)) where
//   nd = log((|i-j|+eps)*c + 1 + eps) / log(|c*(max(i,thr)+eps)| + 1 + eps)
//   MLP: relu(nd*w1 + b1) dot w2 + b2   (1 -> 32 -> 12)
//
// Optimization: MLP output per head is piecewise-linear in nd with <=32
// breakpoints t_w = -b1_w/w1_w. Precompute sorted thresholds + per-interval
// (alpha,beta) per head; main kernel does binary search + 1 FMA per head.
// Output is 201 MB fp32 -> kernel should be HBM-write-bound (~35-45 us).

#define SDIM 2048
#define WDIM 32
#define HDIM 12
#define NK 33            // intervals = WDIM + 1
#define EPSF 1e-6f
#define LOGB 1.0f

// ws layout (floats):
//   [0..63]           sorted thresholds, padded to 64 with +INF
//   [64..64+2*NK*HDIM) interleaved (alpha,beta) per (k,h)
#define WS_T 0
#define WS_AB 64
#define WS_TOTAL (64 + 2 * NK * HDIM)   // 856 floats = 3424 B

__global__ __launch_bounds__(512) void fire_precompute(
    const float* __restrict__ w1, const float* __restrict__ b1,
    const float* __restrict__ w2, const float* __restrict__ b2,
    float* __restrict__ ws)
{
    __shared__ float traw[WDIM], w1s[WDIM], b1s[WDIM];
    __shared__ int rnk[WDIM], neg[WDIM];
    const int tid = threadIdx.x;

    if (tid < WDIM) {
        float a = w1[tid], b = b1[tid];
        w1s[tid] = a; b1s[tid] = b;
        float t; int isneg;
        if (a > 0.f)      { t = -b / a; isneg = 0; }
        else if (a < 0.f) { t = -b / a; isneg = 1; }
        else {
            // w1==0: relu(b1) constant. Treat as positive-slope unit that is
            // "always active" (t=-inf) if b1>0, "never active" (t=+inf) else.
            t = (b > 0.f) ? -INFINITY : INFINITY; isneg = 0;
        }
        traw[tid] = t; neg[tid] = isneg;
    }
    __syncthreads();

    if (tid < WDIM) {
        // rank via O(W^2) counting sort (ties broken by index)
        float t = traw[tid];
        int r = 0;
        for (int v = 0; v < WDIM; ++v) {
            float tv = traw[v];
            if (tv < t || (tv == t && v < tid)) r++;
        }
        rnk[tid] = r;
        ws[WS_T + r] = t;
    } else if (tid < 64) {
        ws[WS_T + tid] = INFINITY;   // pad for 6-step binary search
    }
    __syncthreads();

    // interval k: t_sorted[k-1] <= nd < t_sorted[k]  (k in [0,32])
    // positive-slope w active iff rank(w) < k; negative-slope iff rank(w) >= k
    if (tid < NK * HDIM) {
        const int k = tid % NK;
        const int h = tid / NK;
        float a = 0.f, bb = 0.f;
        for (int w = 0; w < WDIM; ++w) {
            const bool active = neg[w] ? (rnk[w] >= k) : (rnk[w] < k);
            if (active) {
                float w2v = w2[h * WDIM + w];
                a  += w2v * w1s[w];
                bb += w2v * b1s[w];
            }
        }
        bb += b2[h];
        ws[WS_AB + (k * HDIM + h) * 2 + 0] = a;
        ws[WS_AB + (k * HDIM + h) * 2 + 1] = bb;
    }
}

__global__ __launch_bounds__(512) void fire_main(
    const float* __restrict__ ws,
    const float* __restrict__ cptr, const float* __restrict__ lmptr,
    const float* __restrict__ ilptr, float* __restrict__ out)
{
    __shared__ float sT[64];
    __shared__ float sAB[2 * NK * HDIM];
    const int tid = threadIdx.x;

    if (tid < 64) sT[tid] = ws[WS_T + tid];
    for (int idx = tid; idx < 2 * NK * HDIM; idx += 512) sAB[idx] = ws[WS_AB + idx];
    __syncthreads();

    const int i = blockIdx.x;
    const float c   = cptr[0];
    const float thr = fabsf(lmptr[0] * ilptr[0]);
    const float pn  = fmaxf((float)i, thr) + EPSF;
    const float inv_ln = 1.0f / logf(fabsf(c * pn) + LOGB + EPSF);

    const int j0 = tid * 4;           // 512 threads * 4 = 2048 = one row
    float nd[4];
    int kk[4];
    #pragma unroll
    for (int e = 0; e < 4; ++e) {
        int j = j0 + e;
        int dd = i - j; if (dd < 0) dd = -dd;
        float ar = (float)dd + EPSF;
        float x  = fmaf(ar, c, LOGB + EPSF);
        float ndv = logf(x) * inv_ln;
        nd[e] = ndv;
        // branchless lower_bound over 64-padded sorted thresholds -> k in [0,32]
        int k = 0;
        if (ndv > sT[k + 31]) k += 32;
        if (ndv > sT[k + 15]) k += 16;
        if (ndv > sT[k + 7])  k += 8;
        if (ndv > sT[k + 3])  k += 4;
        if (ndv > sT[k + 1])  k += 2;
        if (ndv > sT[k])      k += 1;
        kk[e] = k;
    }

    const size_t base = (size_t)i * SDIM + (size_t)j0;
    #pragma unroll
    for (int h = 0; h < HDIM; ++h) {
        float4 v;
        float* vp = &v.x;
        #pragma unroll
        for (int e = 0; e < 4; ++e) {
            int idx = (kk[e] * HDIM + h) * 2;
            vp[e] = fmaf(sAB[idx], nd[e], sAB[idx + 1]);
        }
        *(float4*)(out + (size_t)h * SDIM * SDIM + base) = v;
    }
}

extern "C" void kernel_launch(void* const* d_in, const int* in_sizes, int n_in,
                              void* d_out, int out_size, void* d_ws, size_t ws_size,
                              hipStream_t stream)
{
    // inputs: 0:x (unused, shape only), 1:w1[32], 2:b1[32], 3:w2[12,32],
    //         4:b2[12], 5:c, 6:L_multiplier, 7:init_L
    const float* w1 = (const float*)d_in[1];
    const float* b1 = (const float*)d_in[2];
    const float* w2 = (const float*)d_in[3];
    const float* b2 = (const float*)d_in[4];
    const float* c  = (const float*)d_in[5];
    const float* lm = (const float*)d_in[6];
    const float* il = (const float*)d_in[7];
    float* ws  = (float*)d_ws;
    float* out = (float*)d_out;

    fire_precompute<<<1, 512, 0, stream>>>(w1, b1, w2, b2, ws);
    fire_main<<<SDIM, 512, 0, stream>>>(ws, c, lm, il, out);
}